// Round 12
// baseline (139.581 us; speedup 1.0000x reference)
//
#include <hip/hip_runtime.h>

// Problem constants (fixed by the reference setup)
#define BB 2
#define NN 4096
#define EE 65536
#define MM 4
#define HH 256
#define NPB 32     // nodes per block (one m-slice each) in the fused kernel
#define NXCD 8
#define XPAD 264   // xs row stride in fp16 (528B: 16B-aligned, 2-way LDS alias = free)

typedef float vf4 __attribute__((ext_vector_type(4)));
typedef int vi2 __attribute__((ext_vector_type(2)));
typedef _Float16 vh4 __attribute__((ext_vector_type(4)));
typedef _Float16 f16x8 __attribute__((ext_vector_type(8)));
typedef float f32x4 __attribute__((ext_vector_type(4)));

// ---------------------------------------------------------------------------
// Kernel 1: zero the per-node slot counters
// ---------------------------------------------------------------------------
__global__ void k_zero(int* __restrict__ p, int n) {
  const int i = blockIdx.x * blockDim.x + threadIdx.x;
  if (i < n) p[i] = 0;
}

// ---------------------------------------------------------------------------
// Kernel 2 (k_prep, grid-partitioned; overlaps three independent HBM streams):
//  part A [0, 32768): per-edge coeff (wave/edge) + packed (src,coeff) build
//  part B [32768, 40960): hint f32 -> fp16 copy (same layout) — makes the
//          per-XCD gather slice 2.1MB -> L2-resident (verified r10: 116->78us)
//  part C [40960, 41024): W -> Wt_hi/Wt_lo fp16 split-transpose
// ---------------------------------------------------------------------------
#define PREP_A 32768
#define PREP_B 8192
#define PREP_C 64

__global__ __launch_bounds__(256) void k_prep(const float* __restrict__ edge_fts,
                                              const float* __restrict__ edge_W,
                                              const float* __restrict__ edge_b,
                                              const int* __restrict__ cfg,
                                              int* __restrict__ cnt,
                                              int2* __restrict__ packed,
                                              const float* __restrict__ hint,
                                              _Float16* __restrict__ h16,
                                              const float* __restrict__ W,
                                              _Float16* __restrict__ wt_hi,
                                              _Float16* __restrict__ wt_lo) {
  const int blk = blockIdx.x;
  const int t = threadIdx.x;
  if (blk < PREP_A) {
    // ---- part A: coeff + build ----
    const int widx = blk * 4 + (t >> 6);   // flat edge index b*E+e
    const int lane = t & 63;
    const vf4 ef = __builtin_nontemporal_load(
        reinterpret_cast<const vf4*>(edge_fts + (size_t)widx * HH + lane * 4));
    const float4 wv = *reinterpret_cast<const float4*>(edge_W + lane * 4);
    float s = ef.x * wv.x + ef.y * wv.y + ef.z * wv.z + ef.w * wv.w;
#pragma unroll
    for (int off = 32; off > 0; off >>= 1) s += __shfl_down(s, off);
    if (lane == 0) {
      const int b = widx >> 16;  // E = 65536
      const vi2 st = __builtin_nontemporal_load(
          reinterpret_cast<const vi2*>(cfg + (size_t)widx * 2));  // (src, tgt)
      const int slot = b * NN + st.y;
      const int p = atomicAdd(&cnt[slot], 1);
      if (p < 16) {  // in-degree is exactly 16 by construction
        int2 v;
        v.x = st.x;
        v.y = __float_as_int(s + edge_b[0]);
        packed[(size_t)slot * 16 + p] = v;
      }
    }
  } else if (blk < PREP_A + PREP_B) {
    // ---- part B: hint -> fp16 ----
    const size_t i = (size_t)(blk - PREP_A) * 256 + t;  // float4 index
    const vf4 v = __builtin_nontemporal_load(reinterpret_cast<const vf4*>(hint) + i);
    vh4 h;
    h.x = (_Float16)v.x; h.y = (_Float16)v.y; h.z = (_Float16)v.z; h.w = (_Float16)v.w;
    *(reinterpret_cast<vh4*>(h16) + i) = h;
  } else {
    // ---- part C: Wt split-transpose ----
    const int jb = blk - PREP_A - PREP_B;   // 0..63
    const int j = jb * 4 + (t >> 6);        // output row of Wt = column of W
    const int h0 = (t & 63) * 4;
    float w0 = W[(size_t)(h0 + 0) * HH + j];
    float w1 = W[(size_t)(h0 + 1) * HH + j];
    float w2 = W[(size_t)(h0 + 2) * HH + j];
    float w3 = W[(size_t)(h0 + 3) * HH + j];
    vh4 hi, lo;
    hi.x = (_Float16)w0; lo.x = (_Float16)(w0 - (float)hi.x);
    hi.y = (_Float16)w1; lo.y = (_Float16)(w1 - (float)hi.y);
    hi.z = (_Float16)w2; lo.z = (_Float16)(w2 - (float)hi.z);
    hi.w = (_Float16)w3; lo.w = (_Float16)(w3 - (float)hi.w);
    *reinterpret_cast<vh4*>(wt_hi + (size_t)j * HH + h0) = hi;
    *reinterpret_cast<vh4*>(wt_lo + (size_t)j * HH + h0) = lo;
  }
}

__device__ __forceinline__ float4 fmax4(const float4& a, const float4& b) {
  return make_float4(fmaxf(a.x, b.x), fmaxf(a.y, b.y), fmaxf(a.z, b.z), fmaxf(a.w, b.w));
}

__device__ __forceinline__ float4 scmul(float c, const vh4& h) {
  return make_float4(c * (float)h.x, c * (float)h.y, c * (float)h.z, c * (float)h.w);
}

// ---------------------------------------------------------------------------
// Kernel 3 (fused, XCD-sharded, fp16 gather + MFMA GEMM):
// block = (unit, chunk), unit = blockIdx%8 = b*4+m -> per-XCD L2-resident
// hint slice (verified r7/r10).
// r12 fix vs r11: stage 1 was latency-serialized (VGPR=52 forced chunked
// loads; VALUBusy fell to 17% once the GEMM VALU no longer hid the stall).
// Now: __launch_bounds__(256,4) (VGPR cap 128, occupancy still LDS-limited
// at 4 blk/CU), 2-row x 16 load batches issued before ANY consume (32
// independent loads in flight), readfirstlane'd wave-uniform src indices
// (scalar base addressing, frees ~32 addr VGPRs), tree-fmax.
// ---------------------------------------------------------------------------
__global__ __launch_bounds__(256, 4) void k_fused(const _Float16* __restrict__ h16,
                                                  const float* __restrict__ node_fts,
                                                  const int2* __restrict__ packed,
                                                  const _Float16* __restrict__ wt_hi,
                                                  const _Float16* __restrict__ wt_lo,
                                                  const float* __restrict__ bias,
                                                  float* __restrict__ out) {
  __shared__ _Float16 xs_hi[NPB][XPAD];  // 16.9 KB
  __shared__ _Float16 xs_lo[NPB][XPAD];  // 16.9 KB
  __shared__ int ssrc[NPB][16];          // 2 KB
  __shared__ float scf[NPB][16];         // 2 KB

  const int t = threadIdx.x;
  const int unit = blockIdx.x & (NXCD - 1);   // = b*4 + m  (XCD-pinned slice)
  const int chunk = blockIdx.x >> 3;
  const int b = unit >> 2;
  const int m = unit & 3;
  const int n0 = chunk * NPB;
  const int w = t >> 6;
  const int lane = t & 63;
  const int r0 = w * 8;

  // ---- stage 0: stage this wave's 8 rows' (src,coeff) pairs ----
#pragma unroll
  for (int q = 0; q < 2; ++q) {
    const int idx = q * 64 + lane;      // 0..127
    const int i = idx >> 4, k = idx & 15;
    const int node = b * NN + n0 + r0 + i;
    const int2 v = packed[(size_t)node * 16 + k];
    ssrc[r0 + i][k] = v.x;
    scf[r0 + i][k] = __int_as_float(v.y);
  }

  // per-thread base into h16 for (b, m, lane)
  const _Float16* hb = h16 + (size_t)b * NN * MM * HH + m * HH + lane * 4;

  // ---- stage 1: fp16 gather in 2-row batches (32 loads in flight) ----
#pragma unroll 1
  for (int ip = 0; ip < 4; ++ip) {
    const int lrA = r0 + ip * 2;
    const int lrB = lrA + 1;
    vh4 hA[16], hB[16];
#pragma unroll
    for (int k = 0; k < 16; ++k) {
      const int sA = __builtin_amdgcn_readfirstlane(ssrc[lrA][k]);
      hA[k] = *reinterpret_cast<const vh4*>(hb + (size_t)sA * (MM * HH));
    }
#pragma unroll
    for (int k = 0; k < 16; ++k) {
      const int sB = __builtin_amdgcn_readfirstlane(ssrc[lrB][k]);
      hB[k] = *reinterpret_cast<const vh4*>(hb + (size_t)sB * (MM * HH));
    }

    // ---- consume row A: scale + tree-max + node_fts + split-store ----
    {
      float4 t8[8];
#pragma unroll
      for (int k = 0; k < 8; ++k)
        t8[k] = fmax4(scmul(scf[lrA][2 * k], hA[2 * k]),
                      scmul(scf[lrA][2 * k + 1], hA[2 * k + 1]));
#pragma unroll
      for (int k = 0; k < 4; ++k) t8[k] = fmax4(t8[k], t8[k + 4]);
      t8[0] = fmax4(t8[0], t8[2]);
      t8[1] = fmax4(t8[1], t8[3]);
      const float4 a = fmax4(t8[0], t8[1]);
      const vf4 nf = __builtin_nontemporal_load(reinterpret_cast<const vf4*>(
          node_fts + (((size_t)(b * NN + n0 + lrA) * MM + m) * HH) + lane * 4));
      const float x0 = nf.x + a.x, x1 = nf.y + a.y, x2 = nf.z + a.z, x3 = nf.w + a.w;
      vh4 hi, lo;
      hi.x = (_Float16)x0; lo.x = (_Float16)(x0 - (float)hi.x);
      hi.y = (_Float16)x1; lo.y = (_Float16)(x1 - (float)hi.y);
      hi.z = (_Float16)x2; lo.z = (_Float16)(x2 - (float)hi.z);
      hi.w = (_Float16)x3; lo.w = (_Float16)(x3 - (float)hi.w);
      *reinterpret_cast<vh4*>(&xs_hi[lrA][lane * 4]) = hi;
      *reinterpret_cast<vh4*>(&xs_lo[lrA][lane * 4]) = lo;
    }
    // ---- consume row B ----
    {
      float4 t8[8];
#pragma unroll
      for (int k = 0; k < 8; ++k)
        t8[k] = fmax4(scmul(scf[lrB][2 * k], hB[2 * k]),
                      scmul(scf[lrB][2 * k + 1], hB[2 * k + 1]));
#pragma unroll
      for (int k = 0; k < 4; ++k) t8[k] = fmax4(t8[k], t8[k + 4]);
      t8[0] = fmax4(t8[0], t8[2]);
      t8[1] = fmax4(t8[1], t8[3]);
      const float4 a = fmax4(t8[0], t8[1]);
      const vf4 nf = __builtin_nontemporal_load(reinterpret_cast<const vf4*>(
          node_fts + (((size_t)(b * NN + n0 + lrB) * MM + m) * HH) + lane * 4));
      const float x0 = nf.x + a.x, x1 = nf.y + a.y, x2 = nf.z + a.z, x3 = nf.w + a.w;
      vh4 hi, lo;
      hi.x = (_Float16)x0; lo.x = (_Float16)(x0 - (float)hi.x);
      hi.y = (_Float16)x1; lo.y = (_Float16)(x1 - (float)hi.y);
      hi.z = (_Float16)x2; lo.z = (_Float16)(x2 - (float)hi.z);
      hi.w = (_Float16)x3; lo.w = (_Float16)(x3 - (float)hi.w);
      *reinterpret_cast<vh4*>(&xs_hi[lrB][lane * 4]) = hi;
      *reinterpret_cast<vh4*>(&xs_lo[lrB][lane * 4]) = lo;
    }
  }
  __syncthreads();  // stage 2 reads rows produced by other waves

  // ---- stage 2: MFMA GEMM [32x256] = xs[32x256] @ W[256x256] ----
  // wave w: row-tile rt=w&1, col-tiles (w>>1)*8..+7; per lane:
  // A[row=l&15][k=(l>>4)*8+0..7], B[k][col=l&15] from Wt rows,
  // D[row=(l>>4)*4+r][col=l&15]. (layout validated r11: absmax unchanged)
  const int rt = w & 1;             // row tile (16 rows)
  const int cb = (w >> 1) * 8;      // col-tile base (8 tiles of 16 cols)
  const int lrow = rt * 16 + (lane & 15);
  const int kg = lane >> 4;         // 0..3: k-subgroup (8 consecutive k)

  f16x8 ahi[8], alo[8];
#pragma unroll
  for (int kt = 0; kt < 8; ++kt) {
    ahi[kt] = *reinterpret_cast<const f16x8*>(&xs_hi[lrow][kt * 32 + kg * 8]);
    alo[kt] = *reinterpret_cast<const f16x8*>(&xs_lo[lrow][kt * 32 + kg * 8]);
  }

#pragma unroll 1
  for (int ct = 0; ct < 8; ++ct) {
    const int j = (cb + ct) * 16 + (lane & 15);
    const _Float16* bh = wt_hi + (size_t)j * HH + kg * 8;
    const _Float16* bl = wt_lo + (size_t)j * HH + kg * 8;
    f32x4 acc = {0.f, 0.f, 0.f, 0.f};
#pragma unroll
    for (int kt = 0; kt < 8; ++kt) {
      const f16x8 bhi = *reinterpret_cast<const f16x8*>(bh + kt * 32);
      const f16x8 blo = *reinterpret_cast<const f16x8*>(bl + kt * 32);
      acc = __builtin_amdgcn_mfma_f32_16x16x32_f16(ahi[kt], bhi, acc, 0, 0, 0);
      acc = __builtin_amdgcn_mfma_f32_16x16x32_f16(alo[kt], bhi, acc, 0, 0, 0);
      acc = __builtin_amdgcn_mfma_f32_16x16x32_f16(ahi[kt], blo, acc, 0, 0, 0);
    }
    const float bj = bias[j];
#pragma unroll
    for (int r = 0; r < 4; ++r) {
      const int n = n0 + rt * 16 + kg * 4 + r;
      __builtin_nontemporal_store(
          acc[r] + bj, out + (((size_t)(b * NN + n) * MM + m) * HH) + j);
    }
  }
}

// ---------------------------------------------------------------------------
extern "C" void kernel_launch(void* const* d_in, const int* in_sizes, int n_in,
                              void* d_out, int out_size, void* d_ws, size_t ws_size,
                              hipStream_t stream) {
  const int* cfg = (const int*)d_in[0];          // [B,E,2]
  const float* hint = (const float*)d_in[1];     // [B,N,M,H]
  const float* node_fts = (const float*)d_in[2]; // [B,N,M,H]
  const float* edge_fts = (const float*)d_in[3]; // [B,E,H]
  const float* edge_W = (const float*)d_in[4];   // [H,1]
  const float* edge_b = (const float*)d_in[5];   // [1]
  const float* update_W = (const float*)d_in[6]; // [H,H]
  const float* update_b = (const float*)d_in[7]; // [H]
  float* out = (float*)d_out;

  char* ws = (char*)d_ws;
  int* cnt = (int*)ws;                                           // 32 KB
  int2* packed = (int2*)(ws + 32768);                            // B*N*16 int2 = 1 MB
  _Float16* h16 = (_Float16*)(ws + 32768 + 1048576);             // 16.78 MB
  _Float16* wt_hi = (_Float16*)(ws + 32768 + 1048576 + 16777216);          // 128 KB
  _Float16* wt_lo = (_Float16*)(ws + 32768 + 1048576 + 16777216 + 131072); // 128 KB

  // 1) zero slot counters
  k_zero<<<(BB * NN + 255) / 256, 256, 0, stream>>>(cnt, BB * NN);
  // 2) fused prep: coeff+build || hint->fp16 || Wt split-transpose
  k_prep<<<PREP_A + PREP_B + PREP_C, 256, 0, stream>>>(
      edge_fts, edge_W, edge_b, cfg, cnt, packed, hint, h16, update_W, wt_hi, wt_lo);
  // 3) fused gather-max + MFMA linear update; grid unit-major for XCD sharding
  k_fused<<<BB * MM * (NN / NPB), 256, 0, stream>>>(h16, node_fts, packed,
                                                    wt_hi, wt_lo, update_b, out);
}

// Round 13
// 113.478 us; speedup vs baseline: 1.2300x; 1.2300x over previous
//
#include <hip/hip_runtime.h>

// Problem constants (fixed by the reference setup)
#define BB 2
#define NN 4096
#define EE 65536
#define MM 4
#define HH 256
#define NPB 32     // nodes per block (one m-slice each) in the fused kernel
#define NXCD 8
#define XPAD 264   // xs row stride in fp16 (528B: 16B-aligned, 2-way LDS alias = free)

typedef float vf4 __attribute__((ext_vector_type(4)));
typedef int vi2 __attribute__((ext_vector_type(2)));
typedef _Float16 vh4 __attribute__((ext_vector_type(4)));
typedef _Float16 f16x8 __attribute__((ext_vector_type(8)));
typedef float f32x4 __attribute__((ext_vector_type(4)));

// ---------------------------------------------------------------------------
// Kernel 1: zero the per-node slot counters
// ---------------------------------------------------------------------------
__global__ void k_zero(int* __restrict__ p, int n) {
  const int i = blockIdx.x * blockDim.x + threadIdx.x;
  if (i < n) p[i] = 0;
}

// ---------------------------------------------------------------------------
// Kernel 2 (k_prep, grid-partitioned; overlaps three independent HBM streams):
//  part A [0, 32768): per-edge coeff (wave/edge) + packed (src,coeff) build
//  part B [32768, 40960): hint f32 -> fp16 copy (same layout) — makes the
//          per-XCD gather slice 2.1MB -> L2-resident (verified r10: 116->78us)
//  part C [40960, 41024): W -> Wt_hi fp16 transpose (single-precision W:
//          dropping the W-lo MFMA term adds ~3e-4 abs error, negligible vs
//          the 0.0625 hint-fp16 floor; halves stage-2 Wt L1 traffic)
// ---------------------------------------------------------------------------
#define PREP_A 32768
#define PREP_B 8192
#define PREP_C 64

__global__ __launch_bounds__(256) void k_prep(const float* __restrict__ edge_fts,
                                              const float* __restrict__ edge_W,
                                              const float* __restrict__ edge_b,
                                              const int* __restrict__ cfg,
                                              int* __restrict__ cnt,
                                              int2* __restrict__ packed,
                                              const float* __restrict__ hint,
                                              _Float16* __restrict__ h16,
                                              const float* __restrict__ W,
                                              _Float16* __restrict__ wt_hi) {
  const int blk = blockIdx.x;
  const int t = threadIdx.x;
  if (blk < PREP_A) {
    // ---- part A: coeff + build ----
    const int widx = blk * 4 + (t >> 6);   // flat edge index b*E+e
    const int lane = t & 63;
    const vf4 ef = __builtin_nontemporal_load(
        reinterpret_cast<const vf4*>(edge_fts + (size_t)widx * HH + lane * 4));
    const float4 wv = *reinterpret_cast<const float4*>(edge_W + lane * 4);
    float s = ef.x * wv.x + ef.y * wv.y + ef.z * wv.z + ef.w * wv.w;
#pragma unroll
    for (int off = 32; off > 0; off >>= 1) s += __shfl_down(s, off);
    if (lane == 0) {
      const int b = widx >> 16;  // E = 65536
      const vi2 st = __builtin_nontemporal_load(
          reinterpret_cast<const vi2*>(cfg + (size_t)widx * 2));  // (src, tgt)
      const int slot = b * NN + st.y;
      const int p = atomicAdd(&cnt[slot], 1);
      if (p < 16) {  // in-degree is exactly 16 by construction
        int2 v;
        v.x = st.x;
        v.y = __float_as_int(s + edge_b[0]);
        packed[(size_t)slot * 16 + p] = v;
      }
    }
  } else if (blk < PREP_A + PREP_B) {
    // ---- part B: hint -> fp16 ----
    const size_t i = (size_t)(blk - PREP_A) * 256 + t;  // float4 index
    const vf4 v = __builtin_nontemporal_load(reinterpret_cast<const vf4*>(hint) + i);
    vh4 h;
    h.x = (_Float16)v.x; h.y = (_Float16)v.y; h.z = (_Float16)v.z; h.w = (_Float16)v.w;
    *(reinterpret_cast<vh4*>(h16) + i) = h;
  } else {
    // ---- part C: Wt transpose (fp16) ----
    const int jb = blk - PREP_A - PREP_B;   // 0..63
    const int j = jb * 4 + (t >> 6);        // output row of Wt = column of W
    const int h0 = (t & 63) * 4;
    vh4 hi;
    hi.x = (_Float16)W[(size_t)(h0 + 0) * HH + j];
    hi.y = (_Float16)W[(size_t)(h0 + 1) * HH + j];
    hi.z = (_Float16)W[(size_t)(h0 + 2) * HH + j];
    hi.w = (_Float16)W[(size_t)(h0 + 3) * HH + j];
    *reinterpret_cast<vh4*>(wt_hi + (size_t)j * HH + h0) = hi;
  }
}

__device__ __forceinline__ float4 fmax4(const float4& a, const float4& b) {
  return make_float4(fmaxf(a.x, b.x), fmaxf(a.y, b.y), fmaxf(a.z, b.z), fmaxf(a.w, b.w));
}

__device__ __forceinline__ float4 scmul(float c, const vh4& h) {
  return make_float4(c * (float)h.x, c * (float)h.y, c * (float)h.z, c * (float)h.w);
}

// ---------------------------------------------------------------------------
// Kernel 3 (fused, XCD-sharded, fp16 gather + MFMA GEMM):
// block = (unit, chunk), unit = blockIdx%8 = b*4+m -> per-XCD L2-resident
// hint slice (verified r7/r10).
// r13 fix vs r11/r12: stage 2's Wt streaming was 512MB through per-CU L1s
// (128KB/wave: 8 ct x 8 kt x 2(hi,lo) x 1KB) — the same W-through-L1 limit
// seen in r5. Dropping the wt_lo path (negligible precision term) halves it;
// MFMA count 3->2 per k-step.
// ---------------------------------------------------------------------------
__global__ __launch_bounds__(256, 4) void k_fused(const _Float16* __restrict__ h16,
                                                  const float* __restrict__ node_fts,
                                                  const int2* __restrict__ packed,
                                                  const _Float16* __restrict__ wt_hi,
                                                  const float* __restrict__ bias,
                                                  float* __restrict__ out) {
  __shared__ _Float16 xs_hi[NPB][XPAD];  // 16.9 KB
  __shared__ _Float16 xs_lo[NPB][XPAD];  // 16.9 KB
  __shared__ int ssrc[NPB][16];          // 2 KB
  __shared__ float scf[NPB][16];         // 2 KB

  const int t = threadIdx.x;
  const int unit = blockIdx.x & (NXCD - 1);   // = b*4 + m  (XCD-pinned slice)
  const int chunk = blockIdx.x >> 3;
  const int b = unit >> 2;
  const int m = unit & 3;
  const int n0 = chunk * NPB;
  const int w = t >> 6;
  const int lane = t & 63;
  const int r0 = w * 8;

  // ---- stage 0: stage this wave's 8 rows' (src,coeff) pairs ----
#pragma unroll
  for (int q = 0; q < 2; ++q) {
    const int idx = q * 64 + lane;      // 0..127
    const int i = idx >> 4, k = idx & 15;
    const int node = b * NN + n0 + r0 + i;
    const int2 v = packed[(size_t)node * 16 + k];
    ssrc[r0 + i][k] = v.x;
    scf[r0 + i][k] = __int_as_float(v.y);
  }

  // per-thread base into h16 for (b, m, lane)
  const _Float16* hb = h16 + (size_t)b * NN * MM * HH + m * HH + lane * 4;

  // ---- stage 1: fp16 gather + scale + tree-max + node_fts; split-store ----
#pragma unroll 1
  for (int i = 0; i < 8; ++i) {
    const int lr = r0 + i;
    const int n = n0 + lr;
    vh4 hv[16];
#pragma unroll
    for (int k = 0; k < 16; ++k) {
      const int s = ssrc[lr][k];
      hv[k] = *reinterpret_cast<const vh4*>(hb + (size_t)s * (MM * HH));
    }
    float4 t8[8];
#pragma unroll
    for (int k = 0; k < 8; ++k)
      t8[k] = fmax4(scmul(scf[lr][2 * k], hv[2 * k]),
                    scmul(scf[lr][2 * k + 1], hv[2 * k + 1]));
#pragma unroll
    for (int k = 0; k < 4; ++k) t8[k] = fmax4(t8[k], t8[k + 4]);
    t8[0] = fmax4(t8[0], t8[2]);
    t8[1] = fmax4(t8[1], t8[3]);
    const float4 a = fmax4(t8[0], t8[1]);
    const vf4 nf = __builtin_nontemporal_load(reinterpret_cast<const vf4*>(
        node_fts + (((size_t)(b * NN + n) * MM + m) * HH) + lane * 4));
    const float x0 = nf.x + a.x, x1 = nf.y + a.y, x2 = nf.z + a.z, x3 = nf.w + a.w;
    vh4 hi, lo;
    hi.x = (_Float16)x0; lo.x = (_Float16)(x0 - (float)hi.x);
    hi.y = (_Float16)x1; lo.y = (_Float16)(x1 - (float)hi.y);
    hi.z = (_Float16)x2; lo.z = (_Float16)(x2 - (float)hi.z);
    hi.w = (_Float16)x3; lo.w = (_Float16)(x3 - (float)hi.w);
    *reinterpret_cast<vh4*>(&xs_hi[lr][lane * 4]) = hi;
    *reinterpret_cast<vh4*>(&xs_lo[lr][lane * 4]) = lo;
  }
  __syncthreads();  // stage 2 reads rows produced by other waves

  // ---- stage 2: MFMA GEMM [32x256] = xs[32x256] @ W[256x256] ----
  // wave w: row-tile rt=w&1, col-tiles (w>>1)*8..+7; per lane:
  // A[row=l&15][k=(l>>4)*8+0..7], B[k][col=l&15] from Wt rows,
  // D[row=(l>>4)*4+r][col=l&15]. (layout validated r11: absmax unchanged)
  const int rt = w & 1;             // row tile (16 rows)
  const int cb = (w >> 1) * 8;      // col-tile base (8 tiles of 16 cols)
  const int lrow = rt * 16 + (lane & 15);
  const int kg = lane >> 4;         // 0..3: k-subgroup (8 consecutive k)

  f16x8 ahi[8], alo[8];
#pragma unroll
  for (int kt = 0; kt < 8; ++kt) {
    ahi[kt] = *reinterpret_cast<const f16x8*>(&xs_hi[lrow][kt * 32 + kg * 8]);
    alo[kt] = *reinterpret_cast<const f16x8*>(&xs_lo[lrow][kt * 32 + kg * 8]);
  }

#pragma unroll 1
  for (int ct = 0; ct < 8; ++ct) {
    const int j = (cb + ct) * 16 + (lane & 15);
    const _Float16* bh = wt_hi + (size_t)j * HH + kg * 8;
    f32x4 acc = {0.f, 0.f, 0.f, 0.f};
#pragma unroll
    for (int kt = 0; kt < 8; ++kt) {
      const f16x8 bhi = *reinterpret_cast<const f16x8*>(bh + kt * 32);
      acc = __builtin_amdgcn_mfma_f32_16x16x32_f16(ahi[kt], bhi, acc, 0, 0, 0);
      acc = __builtin_amdgcn_mfma_f32_16x16x32_f16(alo[kt], bhi, acc, 0, 0, 0);
    }
    const float bj = bias[j];
#pragma unroll
    for (int r = 0; r < 4; ++r) {
      const int n = n0 + rt * 16 + kg * 4 + r;
      __builtin_nontemporal_store(
          acc[r] + bj, out + (((size_t)(b * NN + n) * MM + m) * HH) + j);
    }
  }
}

// ---------------------------------------------------------------------------
extern "C" void kernel_launch(void* const* d_in, const int* in_sizes, int n_in,
                              void* d_out, int out_size, void* d_ws, size_t ws_size,
                              hipStream_t stream) {
  const int* cfg = (const int*)d_in[0];          // [B,E,2]
  const float* hint = (const float*)d_in[1];     // [B,N,M,H]
  const float* node_fts = (const float*)d_in[2]; // [B,N,M,H]
  const float* edge_fts = (const float*)d_in[3]; // [B,E,H]
  const float* edge_W = (const float*)d_in[4];   // [H,1]
  const float* edge_b = (const float*)d_in[5];   // [1]
  const float* update_W = (const float*)d_in[6]; // [H,H]
  const float* update_b = (const float*)d_in[7]; // [H]
  float* out = (float*)d_out;

  char* ws = (char*)d_ws;
  int* cnt = (int*)ws;                                           // 32 KB
  int2* packed = (int2*)(ws + 32768);                            // B*N*16 int2 = 1 MB
  _Float16* h16 = (_Float16*)(ws + 32768 + 1048576);             // 16.78 MB
  _Float16* wt_hi = (_Float16*)(ws + 32768 + 1048576 + 16777216);  // 128 KB

  // 1) zero slot counters
  k_zero<<<(BB * NN + 255) / 256, 256, 0, stream>>>(cnt, BB * NN);
  // 2) fused prep: coeff+build || hint->fp16 || Wt transpose
  k_prep<<<PREP_A + PREP_B + PREP_C, 256, 0, stream>>>(
      edge_fts, edge_W, edge_b, cfg, cnt, packed, hint, h16, update_W, wt_hi);
  // 3) fused gather-max + MFMA linear update; grid unit-major for XCD sharding
  k_fused<<<BB * MM * (NN / NPB), 256, 0, stream>>>(h16, node_fts, packed,
                                                    wt_hi, update_b, out);
}

// Round 14
// 99.309 us; speedup vs baseline: 1.4055x; 1.1427x over previous
//
#include <hip/hip_runtime.h>

// Problem constants (fixed by the reference setup)
#define BB 2
#define NN 4096
#define EE 65536
#define MM 4
#define HH 256
#define NPB 32     // nodes per block (one m-slice each) in the fused kernel
#define NXCD 8
#define XPAD 264   // xs row stride in fp16 (528B: 16B-aligned)

typedef float vf4 __attribute__((ext_vector_type(4)));
typedef int vi2 __attribute__((ext_vector_type(2)));
typedef _Float16 vh4 __attribute__((ext_vector_type(4)));
typedef _Float16 f16x8 __attribute__((ext_vector_type(8)));
typedef float f32x4 __attribute__((ext_vector_type(4)));

// ---------------------------------------------------------------------------
// k_prep (grid-partitioned; overlaps three independent HBM streams):
//  part A [0, 8192): per-edge coeff + packed (src,coeff) build, 4 edges/wave
//          (4 independent 1KB loads in flight; r13's 1/wave was latency-bound).
//          NO cnt reset needed: each call adds exactly 16 per node, so
//          atomicAdd(cnt)&15 yields 16 distinct slots per call from ANY start.
//  part B [8192, 16384): hint f32 -> fp16 copy (per-XCD gather slice ->
//          L2-resident; verified r10: 116->78us)
//  part C [16384, 16448): W -> Wt_hi fp16 transpose (single-precision W,
//          verified r13: wt_lo term negligible, -26us)
// ---------------------------------------------------------------------------
#define PREP_A 8192
#define PREP_B 8192
#define PREP_C 64

__global__ __launch_bounds__(256) void k_prep(const float* __restrict__ edge_fts,
                                              const float* __restrict__ edge_W,
                                              const float* __restrict__ edge_b,
                                              const int* __restrict__ cfg,
                                              unsigned int* __restrict__ cnt,
                                              int2* __restrict__ packed,
                                              const float* __restrict__ hint,
                                              _Float16* __restrict__ h16,
                                              const float* __restrict__ W,
                                              _Float16* __restrict__ wt_hi) {
  const int blk = blockIdx.x;
  const int t = threadIdx.x;
  if (blk < PREP_A) {
    // ---- part A: coeff + build, 4 edges per wave ----
    const int e0 = blk * 16 + (t >> 6) * 4;   // first of 4 flat edge indices
    const int lane = t & 63;
    const float4 wv = *reinterpret_cast<const float4*>(edge_W + lane * 4);
    vf4 ef[4];
#pragma unroll
    for (int q = 0; q < 4; ++q)
      ef[q] = __builtin_nontemporal_load(
          reinterpret_cast<const vf4*>(edge_fts + (size_t)(e0 + q) * HH + lane * 4));
    float s[4];
#pragma unroll
    for (int q = 0; q < 4; ++q)
      s[q] = ef[q].x * wv.x + ef[q].y * wv.y + ef[q].z * wv.z + ef[q].w * wv.w;
#pragma unroll
    for (int off = 32; off > 0; off >>= 1) {
#pragma unroll
      for (int q = 0; q < 4; ++q) s[q] += __shfl_down(s[q], off);
    }
    if (lane == 0) {
      const float eb = edge_b[0];
#pragma unroll
      for (int q = 0; q < 4; ++q) {
        const int widx = e0 + q;
        const int b = widx >> 16;  // E = 65536
        const vi2 st = __builtin_nontemporal_load(
            reinterpret_cast<const vi2*>(cfg + (size_t)widx * 2));  // (src, tgt)
        const int slot = b * NN + st.y;
        const unsigned p = atomicAdd(&cnt[slot], 1u) & 15u;  // 16 adds/call -> distinct
        int2 v;
        v.x = st.x;
        v.y = __float_as_int(s[q] + eb);
        packed[(size_t)slot * 16 + p] = v;
      }
    }
  } else if (blk < PREP_A + PREP_B) {
    // ---- part B: hint -> fp16 ----
    const size_t i = (size_t)(blk - PREP_A) * 256 + t;  // float4 index
    const vf4 v = __builtin_nontemporal_load(reinterpret_cast<const vf4*>(hint) + i);
    vh4 h;
    h.x = (_Float16)v.x; h.y = (_Float16)v.y; h.z = (_Float16)v.z; h.w = (_Float16)v.w;
    *(reinterpret_cast<vh4*>(h16) + i) = h;
  } else {
    // ---- part C: Wt transpose (fp16) ----
    const int jb = blk - PREP_A - PREP_B;   // 0..63
    const int j = jb * 4 + (t >> 6);        // output row of Wt = column of W
    const int h0 = (t & 63) * 4;
    vh4 hi;
    hi.x = (_Float16)W[(size_t)(h0 + 0) * HH + j];
    hi.y = (_Float16)W[(size_t)(h0 + 1) * HH + j];
    hi.z = (_Float16)W[(size_t)(h0 + 2) * HH + j];
    hi.w = (_Float16)W[(size_t)(h0 + 3) * HH + j];
    *reinterpret_cast<vh4*>(wt_hi + (size_t)j * HH + h0) = hi;
  }
}

__device__ __forceinline__ float4 fmax4(const float4& a, const float4& b) {
  return make_float4(fmaxf(a.x, b.x), fmaxf(a.y, b.y), fmaxf(a.z, b.z), fmaxf(a.w, b.w));
}

__device__ __forceinline__ float4 scmul(float c, const vh4& h) {
  return make_float4(c * (float)h.x, c * (float)h.y, c * (float)h.z, c * (float)h.w);
}

// ---------------------------------------------------------------------------
// k_fused (XCD-sharded, fp16 gather + MFMA GEMM):
// block = (unit, chunk), unit = blockIdx%8 = b*4+m -> per-XCD L2-resident
// hint slice (verified r7/r10).
// r14 stage-2 restructure: wave w covers col-tiles w*4..w*4+3 and BOTH
// row-tiles (was 8 ct x 1 rt). B-frags (8KB) loaded once per ct feed 32 MFMAs
// (was 16) -> Wt/wave 64->32KB, and acc0/acc1 give two INDEPENDENT MFMA dep
// chains per kt (r13 showed chain structure, not BW, is what stage 2 pays).
// ---------------------------------------------------------------------------
__global__ __launch_bounds__(256, 4) void k_fused(const _Float16* __restrict__ h16,
                                                  const float* __restrict__ node_fts,
                                                  const int2* __restrict__ packed,
                                                  const _Float16* __restrict__ wt_hi,
                                                  const float* __restrict__ bias,
                                                  float* __restrict__ out) {
  __shared__ _Float16 xs_hi[NPB][XPAD];  // 16.9 KB
  __shared__ _Float16 xs_lo[NPB][XPAD];  // 16.9 KB
  __shared__ int ssrc[NPB][16];          // 2 KB
  __shared__ float scf[NPB][16];         // 2 KB

  const int t = threadIdx.x;
  const int unit = blockIdx.x & (NXCD - 1);   // = b*4 + m  (XCD-pinned slice)
  const int chunk = blockIdx.x >> 3;
  const int b = unit >> 2;
  const int m = unit & 3;
  const int n0 = chunk * NPB;
  const int w = t >> 6;
  const int lane = t & 63;
  const int r0 = w * 8;

  // ---- stage 0: stage this wave's 8 rows' (src,coeff) pairs ----
#pragma unroll
  for (int q = 0; q < 2; ++q) {
    const int idx = q * 64 + lane;      // 0..127
    const int i = idx >> 4, k = idx & 15;
    const int node = b * NN + n0 + r0 + i;
    const int2 v = packed[(size_t)node * 16 + k];
    ssrc[r0 + i][k] = v.x;
    scf[r0 + i][k] = __int_as_float(v.y);
  }

  // per-thread base into h16 for (b, m, lane)
  const _Float16* hb = h16 + (size_t)b * NN * MM * HH + m * HH + lane * 4;

  // ---- stage 1: fp16 gather + scale + tree-max + node_fts; split-store ----
#pragma unroll 1
  for (int i = 0; i < 8; ++i) {
    const int lr = r0 + i;
    const int n = n0 + lr;
    vh4 hv[16];
#pragma unroll
    for (int k = 0; k < 16; ++k) {
      const int s = ssrc[lr][k];
      hv[k] = *reinterpret_cast<const vh4*>(hb + (size_t)s * (MM * HH));
    }
    float4 t8[8];
#pragma unroll
    for (int k = 0; k < 8; ++k)
      t8[k] = fmax4(scmul(scf[lr][2 * k], hv[2 * k]),
                    scmul(scf[lr][2 * k + 1], hv[2 * k + 1]));
#pragma unroll
    for (int k = 0; k < 4; ++k) t8[k] = fmax4(t8[k], t8[k + 4]);
    t8[0] = fmax4(t8[0], t8[2]);
    t8[1] = fmax4(t8[1], t8[3]);
    const float4 a = fmax4(t8[0], t8[1]);
    const vf4 nf = __builtin_nontemporal_load(reinterpret_cast<const vf4*>(
        node_fts + (((size_t)(b * NN + n) * MM + m) * HH) + lane * 4));
    const float x0 = nf.x + a.x, x1 = nf.y + a.y, x2 = nf.z + a.z, x3 = nf.w + a.w;
    vh4 hi, lo;
    hi.x = (_Float16)x0; lo.x = (_Float16)(x0 - (float)hi.x);
    hi.y = (_Float16)x1; lo.y = (_Float16)(x1 - (float)hi.y);
    hi.z = (_Float16)x2; lo.z = (_Float16)(x2 - (float)hi.z);
    hi.w = (_Float16)x3; lo.w = (_Float16)(x3 - (float)hi.w);
    *reinterpret_cast<vh4*>(&xs_hi[lr][lane * 4]) = hi;
    *reinterpret_cast<vh4*>(&xs_lo[lr][lane * 4]) = lo;
  }
  __syncthreads();  // stage 2 reads rows produced by other waves

  // ---- stage 2: MFMA GEMM [32x256] = xs[32x256] @ W[256x256] ----
  // wave w: col-tiles w*4..w*4+3, both row-tiles. Per lane (layout validated
  // r11): A[row=l&15][k=(l>>4)*8+0..7], B[k][col=l&15], D[row=(l>>4)*4+r][col].
  const int lr16 = lane & 15;
  const int kg = lane >> 4;         // 0..3: k-subgroup (8 consecutive k)

#pragma unroll 1
  for (int ct = 0; ct < 4; ++ct) {
    const int j = (w * 4 + ct) * 16 + lr16;
    const _Float16* bh = wt_hi + (size_t)j * HH + kg * 8;
    f16x8 bhi[8];
#pragma unroll
    for (int kt = 0; kt < 8; ++kt)
      bhi[kt] = *reinterpret_cast<const f16x8*>(bh + kt * 32);
    f32x4 acc0 = {0.f, 0.f, 0.f, 0.f};
    f32x4 acc1 = {0.f, 0.f, 0.f, 0.f};
#pragma unroll
    for (int kt = 0; kt < 8; ++kt) {
      const int o = kt * 32 + kg * 8;
      const f16x8 a0h = *reinterpret_cast<const f16x8*>(&xs_hi[lr16][o]);
      const f16x8 a1h = *reinterpret_cast<const f16x8*>(&xs_hi[16 + lr16][o]);
      const f16x8 a0l = *reinterpret_cast<const f16x8*>(&xs_lo[lr16][o]);
      const f16x8 a1l = *reinterpret_cast<const f16x8*>(&xs_lo[16 + lr16][o]);
      acc0 = __builtin_amdgcn_mfma_f32_16x16x32_f16(a0h, bhi[kt], acc0, 0, 0, 0);
      acc1 = __builtin_amdgcn_mfma_f32_16x16x32_f16(a1h, bhi[kt], acc1, 0, 0, 0);
      acc0 = __builtin_amdgcn_mfma_f32_16x16x32_f16(a0l, bhi[kt], acc0, 0, 0, 0);
      acc1 = __builtin_amdgcn_mfma_f32_16x16x32_f16(a1l, bhi[kt], acc1, 0, 0, 0);
    }
    const float bj = bias[j];
#pragma unroll
    for (int r = 0; r < 4; ++r) {
      const int na = n0 + kg * 4 + r;         // row-tile 0
      const int nb = na + 16;                 // row-tile 1
      __builtin_nontemporal_store(
          acc0[r] + bj, out + (((size_t)(b * NN + na) * MM + m) * HH) + j);
      __builtin_nontemporal_store(
          acc1[r] + bj, out + (((size_t)(b * NN + nb) * MM + m) * HH) + j);
    }
  }
}

// ---------------------------------------------------------------------------
extern "C" void kernel_launch(void* const* d_in, const int* in_sizes, int n_in,
                              void* d_out, int out_size, void* d_ws, size_t ws_size,
                              hipStream_t stream) {
  const int* cfg = (const int*)d_in[0];          // [B,E,2]
  const float* hint = (const float*)d_in[1];     // [B,N,M,H]
  const float* node_fts = (const float*)d_in[2]; // [B,N,M,H]
  const float* edge_fts = (const float*)d_in[3]; // [B,E,H]
  const float* edge_W = (const float*)d_in[4];   // [H,1]
  const float* edge_b = (const float*)d_in[5];   // [1]
  const float* update_W = (const float*)d_in[6]; // [H,H]
  const float* update_b = (const float*)d_in[7]; // [H]
  float* out = (float*)d_out;

  char* ws = (char*)d_ws;
  unsigned int* cnt = (unsigned int*)ws;                         // 32 KB (never reset)
  int2* packed = (int2*)(ws + 32768);                            // B*N*16 int2 = 1 MB
  _Float16* h16 = (_Float16*)(ws + 32768 + 1048576);             // 16.78 MB
  _Float16* wt_hi = (_Float16*)(ws + 32768 + 1048576 + 16777216);  // 128 KB

  // 1) fused prep: coeff+build || hint->fp16 || Wt transpose (no k_zero:
  //    slot = atomicAdd&15 is self-consistent at any cnt starting value)
  k_prep<<<PREP_A + PREP_B + PREP_C, 256, 0, stream>>>(
      edge_fts, edge_W, edge_b, cfg, cnt, packed, hint, h16, update_W, wt_hi);
  // 2) fused gather-max + MFMA linear update; grid unit-major for XCD sharding
  k_fused<<<BB * MM * (NN / NPB), 256, 0, stream>>>(h16, node_fts, packed,
                                                    wt_hi, update_b, out);
}

// Round 15
// 96.679 us; speedup vs baseline: 1.4438x; 1.0272x over previous
//
#include <hip/hip_runtime.h>

// Problem constants (fixed by the reference setup)
#define BB 2
#define NN 4096
#define EE 65536
#define MM 4
#define HH 256
#define NPB 16     // nodes per block: 2048 blocks = 8/CU (was grid-limited at 4)
#define NXCD 8
#define XPAD 264   // xs row stride in fp16 (528B; 16-row read pattern = 2-way alias, free)

typedef float vf4 __attribute__((ext_vector_type(4)));
typedef int vi2 __attribute__((ext_vector_type(2)));
typedef _Float16 vh4 __attribute__((ext_vector_type(4)));
typedef _Float16 f16x8 __attribute__((ext_vector_type(8)));
typedef float f32x4 __attribute__((ext_vector_type(4)));

// ---------------------------------------------------------------------------
// k_prep (grid-partitioned; overlaps three independent HBM streams):
//  part A [0, 8192): per-edge coeff + packed (src,coeff) build, 4 edges/wave.
//          NO cnt reset needed: each call adds exactly 16 per node, so
//          atomicAdd(cnt)&15 yields 16 distinct slots per call from ANY start.
//  part B [8192, 16384): hint f32 -> fp16 (per-XCD gather slice L2-resident;
//          verified r10)
//  part C [16384, 16448): W -> Wt_hi fp16 transpose (verified r13)
// ---------------------------------------------------------------------------
#define PREP_A 8192
#define PREP_B 8192
#define PREP_C 64

__global__ __launch_bounds__(256) void k_prep(const float* __restrict__ edge_fts,
                                              const float* __restrict__ edge_W,
                                              const float* __restrict__ edge_b,
                                              const int* __restrict__ cfg,
                                              unsigned int* __restrict__ cnt,
                                              int2* __restrict__ packed,
                                              const float* __restrict__ hint,
                                              _Float16* __restrict__ h16,
                                              const float* __restrict__ W,
                                              _Float16* __restrict__ wt_hi) {
  const int blk = blockIdx.x;
  const int t = threadIdx.x;
  if (blk < PREP_A) {
    // ---- part A: coeff + build, 4 edges per wave ----
    const int e0 = blk * 16 + (t >> 6) * 4;   // first of 4 flat edge indices
    const int lane = t & 63;
    const float4 wv = *reinterpret_cast<const float4*>(edge_W + lane * 4);
    vf4 ef[4];
#pragma unroll
    for (int q = 0; q < 4; ++q)
      ef[q] = __builtin_nontemporal_load(
          reinterpret_cast<const vf4*>(edge_fts + (size_t)(e0 + q) * HH + lane * 4));
    float s[4];
#pragma unroll
    for (int q = 0; q < 4; ++q)
      s[q] = ef[q].x * wv.x + ef[q].y * wv.y + ef[q].z * wv.z + ef[q].w * wv.w;
#pragma unroll
    for (int off = 32; off > 0; off >>= 1) {
#pragma unroll
      for (int q = 0; q < 4; ++q) s[q] += __shfl_down(s[q], off);
    }
    if (lane == 0) {
      const float eb = edge_b[0];
#pragma unroll
      for (int q = 0; q < 4; ++q) {
        const int widx = e0 + q;
        const int b = widx >> 16;  // E = 65536
        const vi2 st = __builtin_nontemporal_load(
            reinterpret_cast<const vi2*>(cfg + (size_t)widx * 2));  // (src, tgt)
        const int slot = b * NN + st.y;
        const unsigned p = atomicAdd(&cnt[slot], 1u) & 15u;  // 16 adds/call -> distinct
        int2 v;
        v.x = st.x;
        v.y = __float_as_int(s[q] + eb);
        packed[(size_t)slot * 16 + p] = v;
      }
    }
  } else if (blk < PREP_A + PREP_B) {
    // ---- part B: hint -> fp16 ----
    const size_t i = (size_t)(blk - PREP_A) * 256 + t;  // float4 index
    const vf4 v = __builtin_nontemporal_load(reinterpret_cast<const vf4*>(hint) + i);
    vh4 h;
    h.x = (_Float16)v.x; h.y = (_Float16)v.y; h.z = (_Float16)v.z; h.w = (_Float16)v.w;
    *(reinterpret_cast<vh4*>(h16) + i) = h;
  } else {
    // ---- part C: Wt transpose (fp16) ----
    const int jb = blk - PREP_A - PREP_B;   // 0..63
    const int j = jb * 4 + (t >> 6);        // output row of Wt = column of W
    const int h0 = (t & 63) * 4;
    vh4 hi;
    hi.x = (_Float16)W[(size_t)(h0 + 0) * HH + j];
    hi.y = (_Float16)W[(size_t)(h0 + 1) * HH + j];
    hi.z = (_Float16)W[(size_t)(h0 + 2) * HH + j];
    hi.w = (_Float16)W[(size_t)(h0 + 3) * HH + j];
    *reinterpret_cast<vh4*>(wt_hi + (size_t)j * HH + h0) = hi;
  }
}

__device__ __forceinline__ float4 fmax4(const float4& a, const float4& b) {
  return make_float4(fmaxf(a.x, b.x), fmaxf(a.y, b.y), fmaxf(a.z, b.z), fmaxf(a.w, b.w));
}

__device__ __forceinline__ float4 scmul(float c, const vh4& h) {
  return make_float4(c * (float)h.x, c * (float)h.y, c * (float)h.z, c * (float)h.w);
}

// ---------------------------------------------------------------------------
// k_fused (XCD-sharded, fp16 gather + MFMA GEMM), r15 structure:
// NPB=16 -> 2048 blocks (8/CU, was grid-limited at 4): 2x outstanding gather
// loads per CU for the latency-bound stage 1. xs_lo DROPPED (error +~0.001,
// negligible vs the 0.0625 hint-fp16 floor; same argument verified for wt_lo
// in r13): LDS 37.9 -> 10.4 KB, stage-2 MFMA count halves.
//   stage 0 (intra-wave): thread t stages pair (row t>>4, slot t&15) — each
//           wave covers exactly its own 4 rows; no barrier.
//   stage 1: per row: 16 independent 512B half4 loads, scale, tree-max,
//            + node_fts(NT) -> fp16 -> xs[row]
//   stage 2 (after the single barrier): wave w: col-tiles w*4..+3, rows 0..15.
//           A[row=l&15][k=(l>>4)*8+..], B[k][col=l&15], D[row=(l>>4)*4+r][col]
//           (layout validated r11).
// ---------------------------------------------------------------------------
__global__ __launch_bounds__(256, 8) void k_fused(const _Float16* __restrict__ h16,
                                                  const float* __restrict__ node_fts,
                                                  const int2* __restrict__ packed,
                                                  const _Float16* __restrict__ wt_hi,
                                                  const float* __restrict__ bias,
                                                  float* __restrict__ out) {
  __shared__ _Float16 xs[NPB][XPAD];   // 8.4 KB
  __shared__ int ssrc[NPB][16];        // 1 KB
  __shared__ float scf[NPB][16];       // 1 KB

  const int t = threadIdx.x;
  const int unit = blockIdx.x & (NXCD - 1);   // = b*4 + m  (XCD-pinned slice)
  const int chunk = blockIdx.x >> 3;
  const int b = unit >> 2;
  const int m = unit & 3;
  const int n0 = chunk * NPB;
  const int w = t >> 6;
  const int lane = t & 63;
  const int r0 = w * 4;     // this wave's first local row

  // ---- stage 0 (intra-wave): thread t stages (row t>>4, slot t&15) ----
  {
    const int i = t >> 4, k = t & 15;   // i in [4w, 4w+3] for this wave
    const int2 v = packed[(size_t)(b * NN + n0 + i) * 16 + k];
    ssrc[i][k] = v.x;
    scf[i][k] = __int_as_float(v.y);
  }

  // per-thread base into h16 for (b, m, lane)
  const _Float16* hb = h16 + (size_t)b * NN * MM * HH + m * HH + lane * 4;

  // ---- stage 1: fp16 gather + scale + tree-max + node_fts -> xs (own rows) ----
#pragma unroll 1
  for (int i = 0; i < 4; ++i) {
    const int lr = r0 + i;
    const int n = n0 + lr;
    vh4 hv[16];
#pragma unroll
    for (int k = 0; k < 16; ++k) {
      const int s = ssrc[lr][k];
      hv[k] = *reinterpret_cast<const vh4*>(hb + (size_t)s * (MM * HH));
    }
    float4 t8[8];
#pragma unroll
    for (int k = 0; k < 8; ++k)
      t8[k] = fmax4(scmul(scf[lr][2 * k], hv[2 * k]),
                    scmul(scf[lr][2 * k + 1], hv[2 * k + 1]));
#pragma unroll
    for (int k = 0; k < 4; ++k) t8[k] = fmax4(t8[k], t8[k + 4]);
    t8[0] = fmax4(t8[0], t8[2]);
    t8[1] = fmax4(t8[1], t8[3]);
    const float4 a = fmax4(t8[0], t8[1]);
    const vf4 nf = __builtin_nontemporal_load(reinterpret_cast<const vf4*>(
        node_fts + (((size_t)(b * NN + n) * MM + m) * HH) + lane * 4));
    vh4 xq;
    xq.x = (_Float16)(nf.x + a.x);
    xq.y = (_Float16)(nf.y + a.y);
    xq.z = (_Float16)(nf.z + a.z);
    xq.w = (_Float16)(nf.w + a.w);
    *reinterpret_cast<vh4*>(&xs[lr][lane * 4]) = xq;
  }
  __syncthreads();  // stage 2 reads rows produced by all waves

  // ---- stage 2: MFMA GEMM [16x256] = xs[16x256] @ W[256x256] ----
  const int lr16 = lane & 15;
  const int kg = lane >> 4;         // 0..3: k-subgroup (8 consecutive k)

#pragma unroll 1
  for (int ct = 0; ct < 4; ++ct) {
    const int j = (w * 4 + ct) * 16 + lr16;
    const _Float16* bh = wt_hi + (size_t)j * HH + kg * 8;
    f32x4 acc = {0.f, 0.f, 0.f, 0.f};
#pragma unroll
    for (int kt = 0; kt < 8; ++kt) {
      const f16x8 bhi = *reinterpret_cast<const f16x8*>(bh + kt * 32);
      const f16x8 a = *reinterpret_cast<const f16x8*>(&xs[lr16][kt * 32 + kg * 8]);
      acc = __builtin_amdgcn_mfma_f32_16x16x32_f16(a, bhi, acc, 0, 0, 0);
    }
    const float bj = bias[j];
#pragma unroll
    for (int r = 0; r < 4; ++r) {
      const int n = n0 + kg * 4 + r;
      __builtin_nontemporal_store(
          acc[r] + bj, out + (((size_t)(b * NN + n) * MM + m) * HH) + j);
    }
  }
}

// ---------------------------------------------------------------------------
extern "C" void kernel_launch(void* const* d_in, const int* in_sizes, int n_in,
                              void* d_out, int out_size, void* d_ws, size_t ws_size,
                              hipStream_t stream) {
  const int* cfg = (const int*)d_in[0];          // [B,E,2]
  const float* hint = (const float*)d_in[1];     // [B,N,M,H]
  const float* node_fts = (const float*)d_in[2]; // [B,N,M,H]
  const float* edge_fts = (const float*)d_in[3]; // [B,E,H]
  const float* edge_W = (const float*)d_in[4];   // [H,1]
  const float* edge_b = (const float*)d_in[5];   // [1]
  const float* update_W = (const float*)d_in[6]; // [H,H]
  const float* update_b = (const float*)d_in[7]; // [H]
  float* out = (float*)d_out;

  char* ws = (char*)d_ws;
  unsigned int* cnt = (unsigned int*)ws;                         // 32 KB (never reset)
  int2* packed = (int2*)(ws + 32768);                            // B*N*16 int2 = 1 MB
  _Float16* h16 = (_Float16*)(ws + 32768 + 1048576);             // 16.78 MB
  _Float16* wt_hi = (_Float16*)(ws + 32768 + 1048576 + 16777216);  // 128 KB

  // 1) fused prep: coeff+build || hint->fp16 || Wt transpose
  k_prep<<<PREP_A + PREP_B + PREP_C, 256, 0, stream>>>(
      edge_fts, edge_W, edge_b, cfg, cnt, packed, hint, h16, update_W, wt_hi);
  // 2) fused gather-max + MFMA linear update; grid unit-major for XCD sharding
  k_fused<<<BB * MM * (NN / NPB), 256, 0, stream>>>(h16, node_fts, packed,
                                                    wt_hi, update_b, out);
}